// Round 10
// baseline (264.301 us; speedup 1.0000x reference)
//
#include <hip/hip_runtime.h>
#include <hip/hip_bf16.h>

#define Bq   32
#define Cq   64
#define NPq  192
#define NOq  72
#define PTS  (NPq * NOq)   // 13824
#define REGD 76
#define OUTD 79

typedef __attribute__((ext_vector_type(8))) short short8;
typedef __attribute__((ext_vector_type(4))) float float4v;

__device__ inline unsigned short f2bf(float x) {
    __hip_bfloat16 h = __float2bfloat16(x);
    return *reinterpret_cast<unsigned short*>(&h);
}
__device__ inline float bf2f(unsigned short u) {
    unsigned int x = ((unsigned int)u) << 16;
    float f;
    __builtin_memcpy(&f, &x, 4);
    return f;
}

// ---------------------------------------------------------------------------
// Phase 0 (once): build gated y-blended tables for ALL 3 stages.
// tab[s][b][o][x][c] bf16, x in [0..W] (x=W replicates W-1), c innermost.
// Work unit = (s, b, o, 25-column chunk): columns are independent (y-lerp
// only), so chunking shrinks the per-block serial chain 4x and LDS to 6.5 KB.
// LDS is written TRANSPOSED [x][c] with stride 65 (odd): phase-1 writes are
// stride-65 (conflict-free), phase-2 packed-pair reads are 2-way (free).
// Grid index q*32+b keeps every block of batch b on XCD b%8.
// ---------------------------------------------------------------------------
template<int H, int W, int NCH>
__device__ __forceinline__ void build_chunk(
    const float* __restrict__ feat, unsigned short* __restrict__ tab,
    const float* __restrict__ lw, const int b, const int o, const int chunk,
    float* __restrict__ sT, const int tid)
{
    const int x0 = chunk * 25;
    const bool last = (chunk == NCH - 1);

    const float ys = 1.0f - (float)o * (1.0f / 71.0f);
    const float iy = ys * (float)(H - 1);
    const float fy = floorf(iy);
    const float wy = iy - fy;
    int iy0 = (int)fy; iy0 = iy0 < 0 ? 0 : (iy0 > H - 1 ? H - 1 : iy0);
    const int iy1 = (iy0 + 1 > H - 1) ? H - 1 : iy0 + 1;
    const float gate = 1.0f / (1.0f + __expf(-lw[o]));

    const float* fb = feat + (size_t)b * 64 * H * W;
    const int r0 = iy0 * W + x0, r1 = iy1 * W + x0;

    // phase 1: 64 ch x 25 cols, write transposed sT[xl*65 + c]
    for (int idx = tid; idx < 1600; idx += 256) {
        const int c  = idx / 25;            // compile-time const divisor
        const int xl = idx - c * 25;
        const float* f = fb + c * (H * W);
        const float v = ((1.0f - wy) * f[r0 + xl] + wy * f[r1 + xl]) * gate;
        sT[xl * 65 + c] = v;
    }
    __syncthreads();

    // phase 2: write [x][c] bf16, 2 ch packed per dword store
    unsigned int* to = (unsigned int*)(tab + ((size_t)(b * NOq + o) * (W + 1) + x0) * 64);
    const int tot2 = (last ? 26 : 25) * 32;
    for (int idx = tid; idx < tot2; idx += 256) {
        const int xl = idx >> 5;
        const int cp = idx & 31;
        const int xs = (xl < 25) ? xl : 24;          // pad col replicates W-1
        const unsigned int lo = f2bf(sT[xs * 65 + 2 * cp]);
        const unsigned int hi = f2bf(sT[xs * 65 + 2 * cp + 1]);
        to[xl * 32 + cp] = lo | (hi << 16);
    }
}

__global__ __launch_bounds__(256) void build_tables_kernel(
    const float* __restrict__ f0,   // x2: H=10,W=25
    const float* __restrict__ f1,   // x1: H=20,W=50
    const float* __restrict__ f2,   // x0: H=40,W=100
    const float* __restrict__ lw,
    unsigned short* __restrict__ t0,
    unsigned short* __restrict__ t1,
    unsigned short* __restrict__ t2)
{
    __shared__ float sT[25 * 65];
    const int tid = threadIdx.x;
    const int b   = blockIdx.x & 31;
    const int q   = blockIdx.x >> 5;      // 0 .. 72*7-1
    const int o   = q / 7;
    const int r   = q - o * 7;            // 0:s0c0  1-2:s1c0-1  3-6:s2c0-3

    if (r == 0)      build_chunk<10, 25, 1>(f0, t0, lw, b, o, 0,     sT, tid);
    else if (r <= 2) build_chunk<20, 50, 2>(f1, t1, lw, b, o, r - 1, sT, tid);
    else             build_chunk<40, 100, 4>(f2, t2, lw, b, o, r - 3, sT, tid);
}

// ---------------------------------------------------------------------------
// Fused: table gather + x-lerp + MFMA + relu/pairmax/mean + FULL HEAD.
// (verbatim from R9 — verified)
// ---------------------------------------------------------------------------
template<int W>
__global__ __launch_bounds__(256) void fused_pool_head_kernel(
    const unsigned short* __restrict__ tab,   // [B][72][W+1][64] bf16
    const float* __restrict__ xsrc, const int xstride,
    const float* __restrict__ lsgi,           // [64][64] this stage
    float* __restrict__ sumFeat,              // [B*NP][64]
    const int stage,
    const float* __restrict__ fc_w,  const float* __restrict__ fc_b,
    const float* __restrict__ cls_w, const float* __restrict__ cls_b,
    const float* __restrict__ cls_ow, const float* __restrict__ cls_ob,
    const float* __restrict__ reg_w, const float* __restrict__ reg_b,
    const float* __restrict__ reg_ow, const float* __restrict__ reg_ob,
    const float* __restrict__ loc_w, const float* __restrict__ loc_b,
    const float* __restrict__ loc_ow, const float* __restrict__ loc_ob,
    float* __restrict__ out, float* __restrict__ xs_next)
{
    constexpr int Wp = W + 1;
    __shared__ __align__(16) float sF [8][68];
    __shared__ __align__(16) float sC [8][68];
    __shared__ __align__(16) float sT1[8][68];
    __shared__ __align__(16) float sT2[8][68];
    __shared__ __align__(16) float sWt[4864];

    const int tid  = threadIdx.x;
    const int w    = tid >> 6;
    const int lane = tid & 63;
    const int ng   = blockIdx.x >> 5;         // 0..23
    const int b    = blockIdx.x & 31;
    const int npair = ng * 4 + w;             // 0..95

    // ---------------- pool ----------------
    short8 wf[4][2];
    {
        const int kb = ((lane >> 4) & 3) * 8;
        const int dl = lane & 15;
        #pragma unroll
        for (int ks = 0; ks < 2; ++ks)
            #pragma unroll
            for (int dt = 0; dt < 4; ++dt) {
                union { unsigned short u[8]; short8 v; } pk;
                #pragma unroll
                for (int j = 0; j < 8; ++j)
                    pk.u[j] = f2bf(lsgi[(ks * 32 + kb + j) * 64 + dt * 16 + dl]);
                wf[dt][ks] = pk.v;
            }
    }

    const unsigned short* tb = tab + (size_t)b * NOq * Wp * 64;
    const float* xp = xsrc + (size_t)xstride * b;
    const int m  = lane & 15;
    const int kg = lane >> 4;
    const int nt0 = npair * 9;

    float sums0[4] = {0.f, 0.f, 0.f, 0.f};
    float sums1[4] = {0.f, 0.f, 0.f, 0.f};

    #pragma unroll
    for (int ntl = 0; ntl < 9; ++ntl) {
        const int pt = (nt0 + ntl) * 16 + m;
        const int o  = pt % NOq;
        float ixf = xp[pt] * (float)(W - 1);
        ixf = fminf(fmaxf(ixf, 0.0f), (float)(W - 1));
        const float fx = floorf(ixf);
        const float wx = ixf - fx;
        const int ix0 = (int)fx;

        const unsigned short* col = tb + ((size_t)o * Wp + ix0) * 64 + kg * 8;
        union { unsigned short u[8]; short8 v; } t00, t01, t10, t11, a0, a1;
        t00.v = *(const short8*)(col);
        t01.v = *(const short8*)(col + 64);
        t10.v = *(const short8*)(col + 32);
        t11.v = *(const short8*)(col + 96);
        #pragma unroll
        for (int j = 0; j < 8; ++j) {
            const float l0 = bf2f(t00.u[j]), h0 = bf2f(t01.u[j]);
            const float l1 = bf2f(t10.u[j]), h1 = bf2f(t11.u[j]);
            a0.u[j] = f2bf(l0 + wx * (h0 - l0));
            a1.u[j] = f2bf(l1 + wx * (h1 - l1));
        }

        const bool hi = (ntl * 16 + (kg * 4)) >= NOq;
        #pragma unroll
        for (int dt = 0; dt < 4; ++dt) {
            float4v c = {0.f, 0.f, 0.f, 0.f};
            c = __builtin_amdgcn_mfma_f32_16x16x32_bf16(a0.v, wf[dt][0], c, 0, 0, 0);
            c = __builtin_amdgcn_mfma_f32_16x16x32_bf16(a1.v, wf[dt][1], c, 0, 0, 0);
            const float pm0 = fmaxf(fmaxf(c[0], c[1]), 0.f);
            const float pm1 = fmaxf(fmaxf(c[2], c[3]), 0.f);
            const float add = pm0 + pm1;
            if (hi) sums1[dt] += add; else sums0[dt] += add;
        }
    }

    #pragma unroll
    for (int dt = 0; dt < 4; ++dt) {
        float v0 = sums0[dt], v1 = sums1[dt];
        v0 += __shfl_xor(v0, 16); v0 += __shfl_xor(v0, 32);
        v1 += __shfl_xor(v1, 16); v1 += __shfl_xor(v1, 32);
        sums0[dt] = v0; sums1[dt] = v1;
    }

    const float invS = 1.0f / (float)(stage + 1);
    if (lane < 16) {
        const size_t row0 = (size_t)(b * NPq + npair * 2) * 64;
        #pragma unroll
        for (int dt = 0; dt < 4; ++dt) {
            const int d = dt * 16 + lane;
            float t0 = sums0[dt] * (1.0f / 36.0f);
            float t1 = sums1[dt] * (1.0f / 36.0f);
            float* p0 = sumFeat + row0 + d;
            float* p1 = sumFeat + row0 + 64 + d;
            if (stage > 0) { t0 += *p0; t1 += *p1; }
            *p0 = t0; *p1 = t1;
            sF[2 * w][d]     = t0 * invS;
            sF[2 * w + 1][d] = t1 * invS;
        }
    }

    // ---------------- head (8 points, in-block) ----------------
    const int pt2 = tid >> 5;          // 0..7 local point
    const int dh  = tid & 31;
    const int d0  = dh * 2;
    const int p0g = b * NPq + ng * 8;  // global point base

    auto gemm64 = [&](const float (*src)[68], float (*dst)[68],
                      const float* __restrict__ gw, const float* __restrict__ gb) {
        __syncthreads();
        #pragma unroll
        for (int i = 0; i < 4; ++i)
            *(float4*)&sWt[(i * 256 + tid) * 4] = *(const float4*)&gw[(i * 256 + tid) * 4];
        __syncthreads();
        float a0 = gb[d0], a1 = gb[d0 + 1];
        #pragma unroll 8
        for (int k = 0; k < 64; ++k) {
            const float av = src[pt2][k];
            const float2 w2 = *(const float2*)&sWt[k * 64 + d0];
            a0 += av * w2.x; a1 += av * w2.y;
        }
        dst[pt2][d0]     = fmaxf(a0, 0.f);
        dst[pt2][d0 + 1] = fmaxf(a1, 0.f);
    };

    gemm64(sF, sC, fc_w, fc_b);

    // ---- cls ----
    gemm64(sC,  sT1, cls_w,        cls_b);
    gemm64(sT1, sT2, cls_w + 4096, cls_b + 64);
    __syncthreads();
    if (tid < 16) {
        const int p = tid >> 1, d = tid & 1;
        float z = cls_ob[d];
        #pragma unroll 8
        for (int k = 0; k < 64; ++k) z += sT2[p][k] * cls_ow[k * 2 + d];
        out[(size_t)(p0g + p) * OUTD + d] = z;
    }

    // ---- reg ----
    gemm64(sC,  sT1, reg_w,        reg_b);
    gemm64(sT1, sT2, reg_w + 4096, reg_b + 64);
    __syncthreads();
    for (int idx = tid; idx < 64 * REGD; idx += 256) sWt[idx] = reg_ow[idx];
    __syncthreads();
    {
        float* orow = out + (size_t)(p0g + pt2) * OUTD;
        float* xsp  = xs_next + (size_t)(p0g + pt2) * NOq;
        for (int j = dh; j < REGD; j += 32) {
            float z = reg_ob[j];
            #pragma unroll 8
            for (int k = 0; k < 64; ++k) z += sT2[pt2][k] * sWt[k * REGD + j];
            orow[2 + j] = z;
            if (j >= 4) xsp[j - 4] = 1.0f / (1.0f + __expf(-z));
        }
    }

    // ---- loc ----
    gemm64(sC,  sT1, loc_w,        loc_b);
    gemm64(sT1, sT2, loc_w + 4096, loc_b + 64);
    __syncthreads();
    if (tid < 8) {
        float z = loc_ob[0];
        #pragma unroll 8
        for (int k = 0; k < 64; ++k) z += sT2[tid][k] * loc_ow[k];
        out[(size_t)(p0g + tid) * OUTD + 78] = z;
    }
}

// ---------------------------------------------------------------------------
extern "C" void kernel_launch(void* const* d_in, const int* in_sizes, int n_in,
                              void* d_out, int out_size, void* d_ws, size_t ws_size,
                              hipStream_t stream)
{
    const float* x0        = (const float*)d_in[0];
    const float* x1        = (const float*)d_in[1];
    const float* x2        = (const float*)d_in[2];
    const float* prior_xs0 = (const float*)d_in[3];
    const float* l_weight  = (const float*)d_in[4];
    const float* lsgi_w    = (const float*)d_in[5];
    const float* fc_w      = (const float*)d_in[6];
    const float* fc_b      = (const float*)d_in[7];
    const float* cls_w     = (const float*)d_in[8];
    const float* cls_b     = (const float*)d_in[9];
    const float* cls_ow    = (const float*)d_in[10];
    const float* cls_ob    = (const float*)d_in[11];
    const float* reg_w     = (const float*)d_in[12];
    const float* reg_b     = (const float*)d_in[13];
    const float* reg_ow    = (const float*)d_in[14];
    const float* reg_ob    = (const float*)d_in[15];
    const float* loc_w     = (const float*)d_in[16];
    const float* loc_b     = (const float*)d_in[17];
    const float* loc_ow    = (const float*)d_in[18];
    const float* loc_ob    = (const float*)d_in[19];

    float* out     = (float*)d_out;
    float* sumFeat = (float*)d_ws;                               // [6144][64] f32
    float* xs      = sumFeat + (size_t)Bq * NPq * Cq;            // [6144][72] f32
    unsigned short* tab0 = (unsigned short*)(xs + (size_t)Bq * PTS);
    unsigned short* tab1 = tab0 + (size_t)Bq * NOq * 26  * 64;   // W=25
    unsigned short* tab2 = tab1 + (size_t)Bq * NOq * 51  * 64;   // W=50

    hipLaunchKernelGGL(build_tables_kernel, dim3(NOq * 7 * Bq), dim3(256), 0, stream,
                       x2, x1, x0, l_weight, tab0, tab1, tab2);

    for (int s = 0; s < 3; ++s) {
        const float* xsrc = (s == 0) ? prior_xs0 : xs;
        const int xstr    = (s == 0) ? 0 : PTS;
        const unsigned short* tb = (s == 0) ? tab0 : (s == 1) ? tab1 : tab2;
        float* outS = out + (size_t)s * Bq * NPq * OUTD;
        if (s == 0)
            hipLaunchKernelGGL((fused_pool_head_kernel<25>), dim3(Bq * 24), dim3(256), 0, stream,
                               tb, xsrc, xstr, lsgi_w + s * 4096, sumFeat, s,
                               fc_w, fc_b, cls_w, cls_b, cls_ow, cls_ob,
                               reg_w, reg_b, reg_ow, reg_ob,
                               loc_w, loc_b, loc_ow, loc_ob, outS, xs);
        else if (s == 1)
            hipLaunchKernelGGL((fused_pool_head_kernel<50>), dim3(Bq * 24), dim3(256), 0, stream,
                               tb, xsrc, xstr, lsgi_w + s * 4096, sumFeat, s,
                               fc_w, fc_b, cls_w, cls_b, cls_ow, cls_ob,
                               reg_w, reg_b, reg_ow, reg_ob,
                               loc_w, loc_b, loc_ow, loc_ob, outS, xs);
        else
            hipLaunchKernelGGL((fused_pool_head_kernel<100>), dim3(Bq * 24), dim3(256), 0, stream,
                               tb, xsrc, xstr, lsgi_w + s * 4096, sumFeat, s,
                               fc_w, fc_b, cls_w, cls_b, cls_ow, cls_ob,
                               reg_w, reg_b, reg_ow, reg_ob,
                               loc_w, loc_b, loc_ow, loc_ob, outS, xs);
    }
}

// Round 11
// 249.726 us; speedup vs baseline: 1.0584x; 1.0584x over previous
//
#include <hip/hip_runtime.h>
#include <hip/hip_bf16.h>

#define Bq   32
#define Cq   64
#define NPq  192
#define NOq  72
#define PTS  (NPq * NOq)   // 13824
#define REGD 76
#define OUTD 79

typedef __attribute__((ext_vector_type(8))) short short8;
typedef __attribute__((ext_vector_type(4))) float float4v;

__device__ inline unsigned short f2bf(float x) {
    __hip_bfloat16 h = __float2bfloat16(x);
    return *reinterpret_cast<unsigned short*>(&h);
}
__device__ inline float bf2f(unsigned short u) {
    unsigned int x = ((unsigned int)u) << 16;
    float f;
    __builtin_memcpy(&f, &x, 4);
    return f;
}

// ---------------------------------------------------------------------------
// Phase 0 (once): build gated y-blended tables for ALL 3 stages.
// EXACT R8 form (measured best: 43.5us; R9/R10 "improvements" both regressed).
// tab[s][b][o][x][c] bf16, x in [0..W] (x=W replicates W-1), c innermost.
// o-major block index (o*96 + s*32+b) keeps each (s,b)'s blocks on one XCD.
// ---------------------------------------------------------------------------
__global__ __launch_bounds__(256) void build_tables_kernel(
    const float* __restrict__ f0,   // x2: H=10,W=25
    const float* __restrict__ f1,   // x1: H=20,W=50
    const float* __restrict__ f2,   // x0: H=40,W=100
    const float* __restrict__ lw,
    unsigned short* __restrict__ t0,
    unsigned short* __restrict__ t1,
    unsigned short* __restrict__ t2)
{
    __shared__ float sRow[64 * 101];

    const int tid = threadIdx.x;
    const int o   = blockIdx.x / 96;
    const int sb  = blockIdx.x - o * 96;
    const int s   = sb >> 5;
    const int b   = sb & 31;

    const float* feat; unsigned short* tab; int H, W;
    if (s == 0)      { feat = f0; tab = t0; H = 10; W = 25; }
    else if (s == 1) { feat = f1; tab = t1; H = 20; W = 50; }
    else             { feat = f2; tab = t2; H = 40; W = 100; }
    const int Wp = W + 1;

    const float ys = 1.0f - (float)o * (1.0f / 71.0f);
    const float iy = ys * (float)(H - 1);
    const float fy = floorf(iy);
    const float wy = iy - fy;
    int iy0 = (int)fy; iy0 = iy0 < 0 ? 0 : (iy0 > H - 1 ? H - 1 : iy0);
    const int iy1 = (iy0 + 1 > H - 1) ? H - 1 : iy0 + 1;
    const float gate = 1.0f / (1.0f + __expf(-lw[o]));

    const float* fb = feat + (size_t)b * 64 * H * W;
    const int iy0W = iy0 * W, iy1W = iy1 * W;

    // blend rows -> LDS [c][x] fp32
    const int tot = 64 * W;
    for (int idx = tid; idx < tot; idx += 256) {
        const int c = idx / W;
        const int x = idx - c * W;
        const float* f = fb + c * (H * W);
        sRow[c * Wp + x] = ((1.0f - wy) * f[iy0W + x] + wy * f[iy1W + x]) * gate;
    }
    __syncthreads();

    // write transposed [x][c] bf16 (c-major coalesced), pad x=W
    unsigned short* to = tab + (size_t)(b * NOq + o) * Wp * 64;
    const int tot2 = Wp * 64;
    for (int idx = tid; idx < tot2; idx += 256) {
        const int x = idx >> 6;
        const int c = idx & 63;
        const int xx = (x < W) ? x : (W - 1);
        to[idx] = f2bf(sRow[c * Wp + xx]);
    }
}

// ---------------------------------------------------------------------------
// Fused: table gather + MFMA with C-SPACE x-lerp + relu/pairmax/mean + HEAD.
// C-space lerp: C = C0 + wx[row]*(C1-C0) where C0/C1 are the two x-tap
// matmuls -- exact by linearity, removes the per-element bf16 lerp+repack.
// Block = (b, group of 8 n), block index ng*32+b (XCD locality).
// ---------------------------------------------------------------------------
template<int W>
__global__ __launch_bounds__(256) void fused_pool_head_kernel(
    const unsigned short* __restrict__ tab,   // [B][72][W+1][64] bf16
    const float* __restrict__ xsrc, const int xstride,
    const float* __restrict__ lsgi,           // [64][64] this stage
    float* __restrict__ sumFeat,              // [B*NP][64]
    const int stage,
    const float* __restrict__ fc_w,  const float* __restrict__ fc_b,
    const float* __restrict__ cls_w, const float* __restrict__ cls_b,
    const float* __restrict__ cls_ow, const float* __restrict__ cls_ob,
    const float* __restrict__ reg_w, const float* __restrict__ reg_b,
    const float* __restrict__ reg_ow, const float* __restrict__ reg_ob,
    const float* __restrict__ loc_w, const float* __restrict__ loc_b,
    const float* __restrict__ loc_ow, const float* __restrict__ loc_ob,
    float* __restrict__ out, float* __restrict__ xs_next)
{
    constexpr int Wp = W + 1;
    __shared__ __align__(16) float sF [8][68];
    __shared__ __align__(16) float sC [8][68];
    __shared__ __align__(16) float sT1[8][68];
    __shared__ __align__(16) float sT2[8][68];
    __shared__ __align__(16) float sWt[4864];

    const int tid  = threadIdx.x;
    const int w    = tid >> 6;
    const int lane = tid & 63;
    const int ng   = blockIdx.x >> 5;         // 0..23
    const int b    = blockIdx.x & 31;
    const int npair = ng * 4 + w;             // 0..95

    // ---------------- pool ----------------
    short8 wf[4][2];
    {
        const int kb = ((lane >> 4) & 3) * 8;
        const int dl = lane & 15;
        #pragma unroll
        for (int ks = 0; ks < 2; ++ks)
            #pragma unroll
            for (int dt = 0; dt < 4; ++dt) {
                union { unsigned short u[8]; short8 v; } pk;
                #pragma unroll
                for (int j = 0; j < 8; ++j)
                    pk.u[j] = f2bf(lsgi[(ks * 32 + kb + j) * 64 + dt * 16 + dl]);
                wf[dt][ks] = pk.v;
            }
    }

    const unsigned short* tb = tab + (size_t)b * NOq * Wp * 64;
    const float* xp = xsrc + (size_t)xstride * b;
    const int m  = lane & 15;
    const int kg = lane >> 4;
    const int nt0 = npair * 9;

    float sums0[4] = {0.f, 0.f, 0.f, 0.f};
    float sums1[4] = {0.f, 0.f, 0.f, 0.f};

    #pragma unroll
    for (int ntl = 0; ntl < 9; ++ntl) {
        const int pt = (nt0 + ntl) * 16 + m;
        const int o  = pt % NOq;
        float ixf = xp[pt] * (float)(W - 1);
        ixf = fminf(fmaxf(ixf, 0.0f), (float)(W - 1));
        const float fx = floorf(ixf);
        const float wx = ixf - fx;
        const int ix0 = (int)fx;

        const unsigned short* col = tb + ((size_t)o * Wp + ix0) * 64 + kg * 8;
        const short8 a00 = *(const short8*)(col);        // tap0, k-lo
        const short8 a01 = *(const short8*)(col + 64);   // tap1, k-lo
        const short8 a10 = *(const short8*)(col + 32);   // tap0, k-hi
        const short8 a11 = *(const short8*)(col + 96);   // tap1, k-hi

        // per-C-row wx (rows kg*4 .. kg*4+3 of this tile)
        float wxr[4];
        #pragma unroll
        for (int j = 0; j < 4; ++j) wxr[j] = __shfl(wx, kg * 4 + j);

        const bool hi = (ntl * 16 + (kg * 4)) >= NOq;
        #pragma unroll
        for (int dt = 0; dt < 4; ++dt) {
            float4v c0 = {0.f, 0.f, 0.f, 0.f};
            float4v c1 = {0.f, 0.f, 0.f, 0.f};
            c0 = __builtin_amdgcn_mfma_f32_16x16x32_bf16(a00, wf[dt][0], c0, 0, 0, 0);
            c0 = __builtin_amdgcn_mfma_f32_16x16x32_bf16(a10, wf[dt][1], c0, 0, 0, 0);
            c1 = __builtin_amdgcn_mfma_f32_16x16x32_bf16(a01, wf[dt][0], c1, 0, 0, 0);
            c1 = __builtin_amdgcn_mfma_f32_16x16x32_bf16(a11, wf[dt][1], c1, 0, 0, 0);
            const float v0 = c0[0] + wxr[0] * (c1[0] - c0[0]);
            const float v1 = c0[1] + wxr[1] * (c1[1] - c0[1]);
            const float v2 = c0[2] + wxr[2] * (c1[2] - c0[2]);
            const float v3 = c0[3] + wxr[3] * (c1[3] - c0[3]);
            const float pm0 = fmaxf(fmaxf(v0, v1), 0.f);
            const float pm1 = fmaxf(fmaxf(v2, v3), 0.f);
            const float add = pm0 + pm1;
            if (hi) sums1[dt] += add; else sums0[dt] += add;
        }
    }

    #pragma unroll
    for (int dt = 0; dt < 4; ++dt) {
        float v0 = sums0[dt], v1 = sums1[dt];
        v0 += __shfl_xor(v0, 16); v0 += __shfl_xor(v0, 32);
        v1 += __shfl_xor(v1, 16); v1 += __shfl_xor(v1, 32);
        sums0[dt] = v0; sums1[dt] = v1;
    }

    const float invS = 1.0f / (float)(stage + 1);
    if (lane < 16) {
        const size_t row0 = (size_t)(b * NPq + npair * 2) * 64;
        #pragma unroll
        for (int dt = 0; dt < 4; ++dt) {
            const int d = dt * 16 + lane;
            float t0 = sums0[dt] * (1.0f / 36.0f);
            float t1 = sums1[dt] * (1.0f / 36.0f);
            float* p0 = sumFeat + row0 + d;
            float* p1 = sumFeat + row0 + 64 + d;
            if (stage > 0) { t0 += *p0; t1 += *p1; }
            *p0 = t0; *p1 = t1;
            sF[2 * w][d]     = t0 * invS;
            sF[2 * w + 1][d] = t1 * invS;
        }
    }

    // ---------------- head (8 points, in-block; verbatim) ----------------
    const int pt2 = tid >> 5;          // 0..7 local point
    const int dh  = tid & 31;
    const int d0  = dh * 2;
    const int p0g = b * NPq + ng * 8;  // global point base

    auto gemm64 = [&](const float (*src)[68], float (*dst)[68],
                      const float* __restrict__ gw, const float* __restrict__ gb) {
        __syncthreads();
        #pragma unroll
        for (int i = 0; i < 4; ++i)
            *(float4*)&sWt[(i * 256 + tid) * 4] = *(const float4*)&gw[(i * 256 + tid) * 4];
        __syncthreads();
        float a0 = gb[d0], a1 = gb[d0 + 1];
        #pragma unroll 8
        for (int k = 0; k < 64; ++k) {
            const float av = src[pt2][k];
            const float2 w2 = *(const float2*)&sWt[k * 64 + d0];
            a0 += av * w2.x; a1 += av * w2.y;
        }
        dst[pt2][d0]     = fmaxf(a0, 0.f);
        dst[pt2][d0 + 1] = fmaxf(a1, 0.f);
    };

    gemm64(sF, sC, fc_w, fc_b);

    // ---- cls ----
    gemm64(sC,  sT1, cls_w,        cls_b);
    gemm64(sT1, sT2, cls_w + 4096, cls_b + 64);
    __syncthreads();
    if (tid < 16) {
        const int p = tid >> 1, d = tid & 1;
        float z = cls_ob[d];
        #pragma unroll 8
        for (int k = 0; k < 64; ++k) z += sT2[p][k] * cls_ow[k * 2 + d];
        out[(size_t)(p0g + p) * OUTD + d] = z;
    }

    // ---- reg ----
    gemm64(sC,  sT1, reg_w,        reg_b);
    gemm64(sT1, sT2, reg_w + 4096, reg_b + 64);
    __syncthreads();
    for (int idx = tid; idx < 64 * REGD; idx += 256) sWt[idx] = reg_ow[idx];
    __syncthreads();
    {
        float* orow = out + (size_t)(p0g + pt2) * OUTD;
        float* xsp  = xs_next + (size_t)(p0g + pt2) * NOq;
        for (int j = dh; j < REGD; j += 32) {
            float z = reg_ob[j];
            #pragma unroll 8
            for (int k = 0; k < 64; ++k) z += sT2[pt2][k] * sWt[k * REGD + j];
            orow[2 + j] = z;
            if (j >= 4) xsp[j - 4] = 1.0f / (1.0f + __expf(-z));
        }
    }

    // ---- loc ----
    gemm64(sC,  sT1, loc_w,        loc_b);
    gemm64(sT1, sT2, loc_w + 4096, loc_b + 64);
    __syncthreads();
    if (tid < 8) {
        float z = loc_ob[0];
        #pragma unroll 8
        for (int k = 0; k < 64; ++k) z += sT2[tid][k] * loc_ow[k];
        out[(size_t)(p0g + tid) * OUTD + 78] = z;
    }
}

// ---------------------------------------------------------------------------
extern "C" void kernel_launch(void* const* d_in, const int* in_sizes, int n_in,
                              void* d_out, int out_size, void* d_ws, size_t ws_size,
                              hipStream_t stream)
{
    const float* x0        = (const float*)d_in[0];
    const float* x1        = (const float*)d_in[1];
    const float* x2        = (const float*)d_in[2];
    const float* prior_xs0 = (const float*)d_in[3];
    const float* l_weight  = (const float*)d_in[4];
    const float* lsgi_w    = (const float*)d_in[5];
    const float* fc_w      = (const float*)d_in[6];
    const float* fc_b      = (const float*)d_in[7];
    const float* cls_w     = (const float*)d_in[8];
    const float* cls_b     = (const float*)d_in[9];
    const float* cls_ow    = (const float*)d_in[10];
    const float* cls_ob    = (const float*)d_in[11];
    const float* reg_w     = (const float*)d_in[12];
    const float* reg_b     = (const float*)d_in[13];
    const float* reg_ow    = (const float*)d_in[14];
    const float* reg_ob    = (const float*)d_in[15];
    const float* loc_w     = (const float*)d_in[16];
    const float* loc_b     = (const float*)d_in[17];
    const float* loc_ow    = (const float*)d_in[18];
    const float* loc_ob    = (const float*)d_in[19];

    float* out     = (float*)d_out;
    float* sumFeat = (float*)d_ws;                               // [6144][64] f32
    float* xs      = sumFeat + (size_t)Bq * NPq * Cq;            // [6144][72] f32
    unsigned short* tab0 = (unsigned short*)(xs + (size_t)Bq * PTS);
    unsigned short* tab1 = tab0 + (size_t)Bq * NOq * 26  * 64;   // W=25
    unsigned short* tab2 = tab1 + (size_t)Bq * NOq * 51  * 64;   // W=50

    hipLaunchKernelGGL(build_tables_kernel, dim3(3 * Bq * NOq), dim3(256), 0, stream,
                       x2, x1, x0, l_weight, tab0, tab1, tab2);

    for (int s = 0; s < 3; ++s) {
        const float* xsrc = (s == 0) ? prior_xs0 : xs;
        const int xstr    = (s == 0) ? 0 : PTS;
        const unsigned short* tb = (s == 0) ? tab0 : (s == 1) ? tab1 : tab2;
        float* outS = out + (size_t)s * Bq * NPq * OUTD;
        if (s == 0)
            hipLaunchKernelGGL((fused_pool_head_kernel<25>), dim3(Bq * 24), dim3(256), 0, stream,
                               tb, xsrc, xstr, lsgi_w + s * 4096, sumFeat, s,
                               fc_w, fc_b, cls_w, cls_b, cls_ow, cls_ob,
                               reg_w, reg_b, reg_ow, reg_ob,
                               loc_w, loc_b, loc_ow, loc_ob, outS, xs);
        else if (s == 1)
            hipLaunchKernelGGL((fused_pool_head_kernel<50>), dim3(Bq * 24), dim3(256), 0, stream,
                               tb, xsrc, xstr, lsgi_w + s * 4096, sumFeat, s,
                               fc_w, fc_b, cls_w, cls_b, cls_ow, cls_ob,
                               reg_w, reg_b, reg_ow, reg_ob,
                               loc_w, loc_b, loc_ow, loc_ob, outS, xs);
        else
            hipLaunchKernelGGL((fused_pool_head_kernel<100>), dim3(Bq * 24), dim3(256), 0, stream,
                               tb, xsrc, xstr, lsgi_w + s * 4096, sumFeat, s,
                               fc_w, fc_b, cls_w, cls_b, cls_ow, cls_ob,
                               reg_w, reg_b, reg_ow, reg_ob,
                               loc_w, loc_b, loc_ow, loc_ob, outS, xs);
    }
}